// Round 7
// baseline (351.167 us; speedup 1.0000x reference)
//
#include <hip/hip_runtime.h>

#define UNITS 14336
#define IN_F 4096
#define PACKED 1024
#define CLIP_VAL 100.0f

typedef unsigned int uint32;

using bf16x8 = __attribute__((ext_vector_type(8))) short;   // 8 bf16 = 4 VGPRs
using f32x4  = __attribute__((ext_vector_type(4))) float;   // 4 fp32 acc

// fp32 -> bf16 round-to-nearest-even
__device__ inline unsigned short f2bf(float f) {
    uint32 u = __float_as_uint(f);
    u += 0x7FFFu + ((u >> 16) & 1u);
    return (unsigned short)(u >> 16);
}

__device__ inline uint32 pack2bf(float a, float b) {
    return (uint32)f2bf(a) | ((uint32)f2bf(b) << 16);
}

// SWAR unpack: one packed byte (int32 value 0..255, 4 crumbs little-endian)
// -> two uint32, each holding 2 bf16: r0 = {bf(c0), bf(c1)}, r1 = {bf(c2), bf(c3)}.
// crumb->bf16: 0->0x0000, 1->0x3F80 (+1), 2->0xBF80 (-1), 3->0x8000 (-0.0, harmless in MAC)
__device__ inline void unpack_byte(int v, uint32& r0, uint32& r1) {
    uint32 t0 = ((uint32)v & 3u) | (((uint32)v & 0xCu) << 14);         // c0 @ [1:0], c1 @ [17:16]
    uint32 t1 = (((uint32)v >> 4) & 3u) | (((uint32)v & 0xC0u) << 10); // c2, c3
    uint32 s0 = t0 >> 1;
    uint32 s1 = t1 >> 1;
    uint32 nz0 = (t0 ^ s0) & 0x00010001u;
    uint32 nz1 = (t1 ^ s1) & 0x00010001u;
    r0 = nz0 * 0x3F80u + ((s0 & 0x00010001u) << 15);
    r1 = nz1 * 0x3F80u + ((s1 & 0x00010001u) << 15);
}

__device__ inline float clipf(float y) {
    return fminf(fmaxf(y, -CLIP_VAL), CLIP_VAL);
}

// k-permuted fragment layout (unchanged from R4/R5):
// "group" g in [0,64) covers original k in [g*64, g*64+64).
// Within a group, lane quad q and k-step s in {0,1}:
//   MFMA k-slot q*8+j  <->  original k = g*64 + q*16 + s*8 + j
// pw side: lane(q,n) reads one dwordx4 = int32 elements {P..P+3}, P = g*16 + q*4;
//   elements P,P+1 -> step s=0 fragment, elements P+2,P+3 -> step s=1 fragment.
// x side: granule idx = g*256 + s*128 + h*64 + lane holds 8 bf16:
//   j -> x[h*16 + (lane&15)][g*64 + (lane>>4)*16 + s*8 + j]

// Kernel 1: convert x [32][4096] fp32 -> bf16 in permuted A-fragment order.
__global__ __launch_bounds__(256) void convert_x_kernel(
    const float* __restrict__ x, uint4* __restrict__ ws) {
    int t = blockIdx.x * 256 + threadIdx.x;      // 0..16383 = granule idx
    int lane = t & 63;
    int h = (t >> 6) & 1;
    int s = (t >> 7) & 1;
    int g = t >> 8;
    int n = lane & 15;
    int q = lane >> 4;
    int b = h * 16 + n;
    int k0 = g * 64 + q * 16 + s * 8;
    const float4* src = (const float4*)(x + (size_t)b * IN_F + k0);
    float4 lo = src[0];
    float4 hi = src[1];
    uint4 o;
    o.x = pack2bf(lo.x, lo.y);
    o.y = pack2bf(lo.z, lo.w);
    o.z = pack2bf(hi.x, hi.y);
    o.w = pack2bf(hi.z, hi.w);
    ws[t] = o;
}

// Kernel 2: MFMA GEMM, v7 — R5 structure + in-kernel x(reps) repeat for
// DIAGNOSIS: repeats make this dispatch long enough to surface in rocprof's
// top-5 with its own counters. acc carries across repeats (prevents elision);
// epilogue folds in 1/reps (exact for reps = power of 2). Same work every call.
__global__ __launch_bounds__(1024, 8) void ternary_mm_kernel(
    const uint4* __restrict__ xw,     // permuted bf16 x fragments
    const int*   __restrict__ pw,     // [UNITS][PACKED] packed bytes as int32
    const float* __restrict__ scale,
    const float* __restrict__ bias,
    float*       __restrict__ out,
    int reps) {
    __shared__ f32x4 red[16][2][64];  // [wave][h][lane] = 32 KB

    const int tid  = threadIdx.x;
    const int wid  = tid >> 6;           // 0..15 = K-split index
    const int lane = tid & 63;
    const int q    = lane >> 4;          // quad 0..3
    const int n    = lane & 15;
    const int u0   = blockIdx.x << 4;    // 16 units per block

    f32x4 acc0 = {0.f,0.f,0.f,0.f};      // batches h0 (0-15)
    f32x4 acc1 = {0.f,0.f,0.f,0.f};      // batches h1 (16-31)

    const int g0 = wid << 2;             // first group (of 64 total)
    const int*   pA = pw + (size_t)(u0 + n) * PACKED + (g0 << 4) + (q << 2);
    const uint4* xb = xw + (g0 << 8) + lane;

    for (int r = 0; r < reps; ++r) {
        #pragma unroll
        for (int i = 0; i < 4; ++i) {
            int4 w4 = *(const int4*)(pA + (i << 4));
            uint4 x00 = xb[(i << 8)];            // s=0, h=0
            uint4 x01 = xb[(i << 8) + 64];       // s=0, h=1
            uint4 x10 = xb[(i << 8) + 128];      // s=1, h=0
            uint4 x11 = xb[(i << 8) + 192];      // s=1, h=1

            uint4 fA, fB;                        // step 0 / step 1 weight frags
            unpack_byte(w4.x, fA.x, fA.y);
            unpack_byte(w4.y, fA.z, fA.w);
            unpack_byte(w4.z, fB.x, fB.y);
            unpack_byte(w4.w, fB.z, fB.w);
            bf16x8 vA = __builtin_bit_cast(bf16x8, fA);
            bf16x8 vB = __builtin_bit_cast(bf16x8, fB);

            acc0 = __builtin_amdgcn_mfma_f32_16x16x32_bf16(
                __builtin_bit_cast(bf16x8, x00), vA, acc0, 0, 0, 0);
            acc1 = __builtin_amdgcn_mfma_f32_16x16x32_bf16(
                __builtin_bit_cast(bf16x8, x01), vA, acc1, 0, 0, 0);
            acc0 = __builtin_amdgcn_mfma_f32_16x16x32_bf16(
                __builtin_bit_cast(bf16x8, x10), vB, acc0, 0, 0, 0);
            acc1 = __builtin_amdgcn_mfma_f32_16x16x32_bf16(
                __builtin_bit_cast(bf16x8, x11), vB, acc1, 0, 0, 0);
        }
    }

    red[wid][0][lane] = acc0;
    red[wid][1][lane] = acc1;
    __syncthreads();

    // Reduce 16 K-partials + epilogue. 128 active threads, one per (h, lane).
    if (tid < 128) {
        const float inv = 1.0f / (float)reps;    // exact for power-of-2 reps
        const int h = tid >> 6;
        const int l = tid & 63;
        f32x4 s = red[0][h][l];
        #pragma unroll
        for (int w = 1; w < 16; ++w) {
            f32x4 v = red[w][h][l];
            s[0] += v[0]; s[1] += v[1]; s[2] += v[2]; s[3] += v[3];
        }
        const int u  = u0 + (l & 15);
        const int b0 = h * 16 + ((l >> 4) << 2);   // row = (lane>>4)*4 + reg
        const float sc = scale[u] * inv;
        const float bi = bias[u];
        float* o = out + (size_t)b0 * UNITS + u;
        o[0 * UNITS] = clipf(s[0] * sc + bi);
        o[1 * UNITS] = clipf(s[1] * sc + bi);
        o[2 * UNITS] = clipf(s[2] * sc + bi);
        o[3 * UNITS] = clipf(s[3] * sc + bi);
    }
}

extern "C" void kernel_launch(void* const* d_in, const int* in_sizes, int n_in,
                              void* d_out, int out_size, void* d_ws, size_t ws_size,
                              hipStream_t stream) {
    const float* x     = (const float*)d_in[0];
    const int*   pw    = (const int*)d_in[1];
    const float* scale = (const float*)d_in[2];
    const float* bias  = (const float*)d_in[3];
    float* out = (float*)d_out;

    // ws usage: 32*4096 bf16 = 256 KB permuted x fragments
    uint4* xw = (uint4*)d_ws;

    convert_x_kernel<<<64, 256, 0, stream>>>(x, xw);
    // reps=8: diagnostic amplification so the MM dispatch surfaces in top-5
    // rocprof rows with its own counters. Marginal cost per rep = L2/L3-warm
    // MM time; rep 1 pays HBM.
    ternary_mm_kernel<<<UNITS / 16, 1024, 0, stream>>>(xw, pw, scale, bias, out, 8);
}

// Round 8
// 104.456 us; speedup vs baseline: 3.3619x; 3.3619x over previous
//
#include <hip/hip_runtime.h>

#define UNITS 14336
#define IN_F 4096
#define PACKED 1024
#define CLIP_VAL 100.0f

typedef unsigned int uint32;

using bf16x8 = __attribute__((ext_vector_type(8))) short;   // 8 bf16 = 4 VGPRs
using f32x4  = __attribute__((ext_vector_type(4))) float;   // 4 fp32 acc

// fp32 -> bf16 round-to-nearest-even
__device__ inline unsigned short f2bf(float f) {
    uint32 u = __float_as_uint(f);
    u += 0x7FFFu + ((u >> 16) & 1u);
    return (unsigned short)(u >> 16);
}

__device__ inline uint32 pack2bf(float a, float b) {
    return (uint32)f2bf(a) | ((uint32)f2bf(b) << 16);
}

// SWAR unpack: one packed byte (int32 value 0..255, 4 crumbs little-endian)
// -> two uint32, each holding 2 bf16: r0 = {bf(c0), bf(c1)}, r1 = {bf(c2), bf(c3)}.
// crumb->bf16: 0->0x0000, 1->0x3F80 (+1), 2->0xBF80 (-1), 3->0x8000 (-0.0, harmless in MAC)
__device__ inline void unpack_byte(int v, uint32& r0, uint32& r1) {
    uint32 t0 = ((uint32)v & 3u) | (((uint32)v & 0xCu) << 14);         // c0 @ [1:0], c1 @ [17:16]
    uint32 t1 = (((uint32)v >> 4) & 3u) | (((uint32)v & 0xC0u) << 10); // c2, c3
    uint32 s0 = t0 >> 1;
    uint32 s1 = t1 >> 1;
    uint32 nz0 = (t0 ^ s0) & 0x00010001u;
    uint32 nz1 = (t1 ^ s1) & 0x00010001u;
    r0 = nz0 * 0x3F80u + ((s0 & 0x00010001u) << 15);
    r1 = nz1 * 0x3F80u + ((s1 & 0x00010001u) << 15);
}

__device__ inline float clipf(float y) {
    return fminf(fmaxf(y, -CLIP_VAL), CLIP_VAL);
}

// k-permuted fragment layout (unchanged):
// "group" g in [0,64) covers original k in [g*64, g*64+64).
// Within a group, lane quad q and k-step s in {0,1}:
//   MFMA k-slot q*8+j  <->  original k = g*64 + q*16 + s*8 + j
// pw side: lane(q,n) needs dwordx4 = int32 elements {P..P+3}, P = g*16 + q*4
//   (= 16-B granule #(g*4+q) of unit row n). Elements P,P+1 -> step s=0,
//   elements P+2,P+3 -> step s=1.
// x side: granule idx = g*256 + s*128 + h*64 + lane holds 8 bf16:
//   j -> x[h*16 + (lane&15)][g*64 + (lane>>4)*16 + s*8 + j]

// Kernel 1: convert x fp32 -> bf16 permuted fragments, replicated 8x
// (one copy per XCD-heuristic slot; MM block reads copy blockIdx&7).
__global__ __launch_bounds__(256) void convert_x_kernel(
    const float* __restrict__ x, uint4* __restrict__ ws) {
    int b = blockIdx.x;                          // 0..511
    int c = b & 7;                               // copy id
    int t = ((b >> 3) << 8) + threadIdx.x;       // granule 0..16383
    int lane = t & 63;
    int h = (t >> 6) & 1;
    int s = (t >> 7) & 1;
    int g = t >> 8;
    int n = lane & 15;
    int q = lane >> 4;
    int bi = h * 16 + n;
    int k0 = g * 64 + q * 16 + s * 8;
    const float4* src = (const float4*)(x + (size_t)bi * IN_F + k0);
    float4 lo = src[0];
    float4 hi = src[1];
    uint4 o;
    o.x = pack2bf(lo.x, lo.y);
    o.y = pack2bf(lo.z, lo.w);
    o.z = pack2bf(hi.x, hi.y);
    o.w = pack2bf(hi.z, hi.w);
    ws[c * 16384 + t] = o;
}

// Kernel 2: MFMA GEMM, v8 — CONTIGUOUS pw streaming.
// R7 diagnosis: the 16-rows-x-64B (4 KB stride) wave read pattern caps HBM at
// ~2.7 TB/s (vs 6.3+ sequential). Fix: stage the block's 64 KB pw tile into
// LDS as a LINEAR image via global_load_lds — each staging instruction reads
// a fully contiguous 1 KB (64 lanes x 16 B). The cross-row fragment gather
// then happens in LDS (ds_read_b128; worst-case conflicts cost ~100 cyc/wave,
// negligible). One barrier; reduce buffer aliases the staging LDS afterwards.
// Grid: 896 blocks x 1024 threads (16 waves). Block tile: 16 units x 32
// batches, K-split 16. 64 KB LDS -> 2 blocks/CU, 32 waves/CU.
__global__ __launch_bounds__(1024, 8) void ternary_mm_kernel(
    const uint4* __restrict__ xw,     // 8 replicated copies of permuted x frags
    const int*   __restrict__ pw,     // [UNITS][PACKED] packed bytes as int32
    const float* __restrict__ scale,
    const float* __restrict__ bias,
    float*       __restrict__ out) {
    __shared__ int lds[16384];        // 64 KB: linear pw tile, later reduce buf

    const int tid  = threadIdx.x;
    const int wid  = tid >> 6;           // 0..15 = K-split index
    const int lane = tid & 63;
    const int q    = lane >> 4;          // quad 0..3
    const int n    = lane & 15;
    const int u0   = blockIdx.x << 4;    // 16 units per block
    const int g0   = wid << 2;           // first group (of 64 total)

    // ---- stage 64 KB pw tile linearly: 4 rounds x 16 waves x 1 KB ----
    {
        const char* src = (const char*)(pw + (size_t)u0 * PACKED);
        #pragma unroll
        for (int r = 0; r < 4; ++r) {
            const int off = ((r * 16 + wid) << 10) + (lane << 4);
            __builtin_amdgcn_global_load_lds(
                (const __attribute__((address_space(1))) uint32*)(src + off),
                (__attribute__((address_space(3))) uint32*)((char*)lds + off),
                16, 0, 0);
        }
    }

    // x fragments from this block's XCD-local copy (prefetch first batch;
    // __syncthreads drains vmcnt anyway, so these are ready after the barrier)
    const uint4* xb = xw + ((blockIdx.x & 7) * 16384) + (g0 << 8) + lane;
    uint4 xa0 = xb[0], xa1 = xb[64], xa2 = xb[128], xa3 = xb[192];

    __syncthreads();                     // DMA drained (vmcnt) + cross-wave vis

    f32x4 acc0 = {0.f,0.f,0.f,0.f};      // batches h0 (0-15)
    f32x4 acc1 = {0.f,0.f,0.f,0.f};      // batches h1 (16-31)
    // fragment read: row n, granule g*4+q  ->  byte n*4096 + (g*4+q)*16
    const char* lb = (const char*)lds + (n << 12) + (q << 4);

    #pragma unroll
    for (int i = 0; i < 4; ++i) {
        uint4 xn0, xn1, xn2, xn3;
        if (i < 3) {                     // rolling 1-iter x prefetch
            const uint4* xi = xb + ((i + 1) << 8);
            xn0 = xi[0]; xn1 = xi[64]; xn2 = xi[128]; xn3 = xi[192];
        }
        int4 w4 = *(const int4*)(lb + ((g0 + i) << 6));    // ds_read_b128

        uint4 fA, fB;                    // step 0 / step 1 weight frags
        unpack_byte(w4.x, fA.x, fA.y);
        unpack_byte(w4.y, fA.z, fA.w);
        unpack_byte(w4.z, fB.x, fB.y);
        unpack_byte(w4.w, fB.z, fB.w);
        bf16x8 vA = __builtin_bit_cast(bf16x8, fA);
        bf16x8 vB = __builtin_bit_cast(bf16x8, fB);

        acc0 = __builtin_amdgcn_mfma_f32_16x16x32_bf16(
            __builtin_bit_cast(bf16x8, xa0), vA, acc0, 0, 0, 0);
        acc1 = __builtin_amdgcn_mfma_f32_16x16x32_bf16(
            __builtin_bit_cast(bf16x8, xa1), vA, acc1, 0, 0, 0);
        acc0 = __builtin_amdgcn_mfma_f32_16x16x32_bf16(
            __builtin_bit_cast(bf16x8, xa2), vB, acc0, 0, 0, 0);
        acc1 = __builtin_amdgcn_mfma_f32_16x16x32_bf16(
            __builtin_bit_cast(bf16x8, xa3), vB, acc1, 0, 0, 0);

        if (i < 3) { xa0 = xn0; xa1 = xn1; xa2 = xn2; xa3 = xn3; }
    }

    __syncthreads();                     // all pw ds_reads done; alias LDS
    f32x4* red = (f32x4*)lds;            // [16 waves][2 h][64 lanes] = 32 KB
    red[(wid * 2 + 0) * 64 + lane] = acc0;
    red[(wid * 2 + 1) * 64 + lane] = acc1;
    __syncthreads();

    // Reduce 16 K-partials + epilogue. 128 active threads, one per (h, lane).
    if (tid < 128) {
        const int h = tid >> 6;
        const int l = tid & 63;
        f32x4 s = red[h * 64 + l];
        #pragma unroll
        for (int w = 1; w < 16; ++w) {
            f32x4 v = red[(w * 2 + h) * 64 + l];
            s[0] += v[0]; s[1] += v[1]; s[2] += v[2]; s[3] += v[3];
        }
        const int u  = u0 + (l & 15);
        const int b0 = h * 16 + ((l >> 4) << 2);   // row = (lane>>4)*4 + reg
        const float sc = scale[u];
        const float bi = bias[u];
        float* o = out + (size_t)b0 * UNITS + u;
        o[0 * UNITS] = clipf(s[0] * sc + bi);
        o[1 * UNITS] = clipf(s[1] * sc + bi);
        o[2 * UNITS] = clipf(s[2] * sc + bi);
        o[3 * UNITS] = clipf(s[3] * sc + bi);
    }
}

extern "C" void kernel_launch(void* const* d_in, const int* in_sizes, int n_in,
                              void* d_out, int out_size, void* d_ws, size_t ws_size,
                              hipStream_t stream) {
    const float* x     = (const float*)d_in[0];
    const int*   pw    = (const int*)d_in[1];
    const float* scale = (const float*)d_in[2];
    const float* bias  = (const float*)d_in[3];
    float* out = (float*)d_out;

    // ws usage: 8 copies x 256 KB permuted bf16 x fragments = 2 MB
    uint4* xw = (uint4*)d_ws;

    convert_x_kernel<<<512, 256, 0, stream>>>(x, xw);
    ternary_mm_kernel<<<UNITS / 16, 1024, 0, stream>>>(xw, pw, scale, bias, out);
}